// Round 12
// baseline (57.258 us; speedup 1.0000x reference)
//
#include <hip/hip_runtime.h>
#include <hip/hip_bf16.h>

#define NB 64
#define NS 1024
#define DD 256
#define NT 36          // upper-triangular 8x8 tile count
#define THR 120.0f     // dist^2 below which exp(-dist) can matter

typedef __attribute__((ext_vector_type(4))) float f32x4;
typedef __attribute__((ext_vector_type(8))) short bf16x8;
typedef __attribute__((ext_vector_type(8))) unsigned short u16x8;
typedef __attribute__((ext_vector_type(4))) unsigned short u16x4;

__device__ __forceinline__ unsigned short f2bf(float x) {
  union { float f; unsigned int u; } c; c.f = x;
  unsigned int r = c.u + 0x7fffu + ((c.u >> 16) & 1u);
  return (unsigned short)(r >> 16);
}

// dbf2 layout (kg-major fragment blocks): block(b, kg, rt) = (b*8 + kg)*64 + rt,
// 512 bf16 each. Slot s (0..63) holds 8 bf16: row = rt*16 + (s&15),
// k = kg*32 + (s>>4)*8 + 0..7.

// ---- prep: blocks [0,4096): 128 thr (2 waves), one 16-row tile per block:
//      wave w loads rows w*8..w*8+7 (coalesced 1KB f32 loads), exact-f32 sq,
//      XOR-swizzled LDS write; barrier; wave w stores kg w*4..w*4+3 as 1KB
//      coalesced fragment stores. LDS 8KB/block -> 16 blocks/CU (32 waves).
//      XCD-matched: XCD k (= px&7) writes batches [8k,8k+8) = main's readers.
//      blocks [4096,5120): denom2/C partials over W/S (no atomics). ----
__global__ __launch_bounds__(128) void prep_kernel(const float* __restrict__ din,
                                                   unsigned short* __restrict__ dbf2,
                                                   float* __restrict__ sq,
                                                   const float* __restrict__ S,
                                                   const float* __restrict__ W,
                                                   float* __restrict__ dpart,
                                                   float* __restrict__ cpart,
                                                   int write_bf) {
  __shared__ unsigned short T[16][256];          // 8 KB
  __shared__ float redD[2], redC[2];
  const int px = (int)blockIdx.x;
  const int wid = (int)threadIdx.x >> 6;         // 0,1
  const int l = (int)threadIdx.x & 63;
  if (px < 4096) {
    const int tb = (px & 7) * 512 + (px >> 3);   // tile task 0..4095
    const int b = tb >> 6, rt = tb & 63;
    const float4* src =
        reinterpret_cast<const float4*>(din + ((size_t)b * NS + rt * 16) * DD) + l;
    #pragma unroll
    for (int j = 0; j < 8; ++j) {
      const int ri = wid * 8 + j;                // row within tile
      float4 v = src[ri * 64];                   // row stride 256 f = 64 float4
      float s = v.x * v.x + v.y * v.y + v.z * v.z + v.w * v.w;
      #pragma unroll
      for (int off = 32; off > 0; off >>= 1) s += __shfl_xor(s, off, 64);
      if (l == 0) sq[(size_t)b * NS + rt * 16 + ri] = s;
      if (write_bf) {
        u16x4 o;
        o[0] = f2bf(v.x); o[1] = f2bf(v.y); o[2] = f2bf(v.z); o[3] = f2bf(v.w);
        const int cp = (l >> 1) ^ (ri & 7);
        *reinterpret_cast<u16x4*>(&T[ri][cp * 8 + (l & 1) * 4]) = o;
      }
    }
    if (!write_bf) return;
    __syncthreads();
    unsigned short* dst = dbf2 + (((size_t)b * 8) * 64 + rt) * 512 + (size_t)l * 8;
    #pragma unroll
    for (int q = 0; q < 4; ++q) {
      const int kg = wid * 4 + q;
      const int cc = (kg * 4 + (l >> 4)) ^ (l & 7);
      u16x8 frag = *reinterpret_cast<const u16x8*>(&T[l & 15][cc * 8]);
      *reinterpret_cast<u16x8*>(dst + (size_t)kg * 64 * 512) = frag;
    }
    return;
  }
  // denomC partials: blk in [0,1024), 128 thr x 2 float4 each
  const int blk = px - 4096;
  float dsum = 0.f, csum = 0.f;
  #pragma unroll
  for (int rpt = 0; rpt < 2; ++rpt) {
    const int idx = blk * 256 + rpt * 128 + (int)threadIdx.x;
    float4 w = reinterpret_cast<const float4*>(W)[idx];
    float4 s4 = reinterpret_cast<const float4*>(S)[idx];
    const int e0 = idx << 2;
    const int r = e0 >> 10, c0 = e0 & 1023;
    float wv[4] = {w.x, w.y, w.z, w.w};
    float sv[4] = {s4.x, s4.y, s4.z, s4.w};
    #pragma unroll
    for (int i = 0; i < 4; ++i) {
      const bool dg = (c0 + i) == r;
      const float a = wv[i] - (dg ? 1.0f : 0.0f);
      dsum = fmaf(a, a, dsum);
      const float bq = dg ? (1.0f - sv[i]) : sv[i];
      csum = fmaf(wv[i] * bq, bq, csum);   // W binary: W^2 == W
    }
  }
  #pragma unroll
  for (int off = 32; off > 0; off >>= 1) {
    dsum += __shfl_xor(dsum, off, 64);
    csum += __shfl_xor(csum, off, 64);
  }
  if (l == 0) { redD[wid] = dsum; redC[wid] = csum; }
  __syncthreads();
  if (threadIdx.x == 0) {
    dpart[blk] = redD[0] + redD[1];
    cpart[blk] = redC[0] + redC[1];
  }
}

// ---- main: 2304 blocks x 128 thr (2 waves). Wave w owns a 64x128 sub-tile
// (rows brow + w*64.., all 128 cols): per kg 4 A-frags + 8 B-frags feed 32
// MFMAs (375 B/MFMA vs 512 at 64x64) -> block L2 traffic 256->192 KB.
// Barrier-free, LDS-free; loads hit the LOCAL XCD L2 (prep placement matched).
// acc[4][8] = 128 regs, total ~205 -> no spill under (128,2).
template <int MODE>
__global__ __launch_bounds__(128, 2) void main_kernel(
    const float* __restrict__ dvec, const unsigned short* __restrict__ dbf2,
    const float* __restrict__ sq, float* __restrict__ npart,
    const float* __restrict__ S, const float* __restrict__ W) {
  const int tid = threadIdx.x;
  const int lane = tid & 63;
  const int wid = tid >> 6;          // 0,1

  // XCD-chunked bijective swizzle (2304 = 8 * 288): XCD k gets bids
  // [288k, 288k+288) -> b in [8k, 8k+8) (t-fast) = the batches its L2 holds.
  const int orig = (int)blockIdx.x;
  const int bid = (orig & 7) * (NT * NB / 8) + (orig >> 3);
  const int t = bid % NT;
  const int b = bid / NT;
  int u = t, ti = 0;
  while (u >= 8 - ti) { u -= 8 - ti; ++ti; }
  const int tj = ti + u;
  const int brow = ti * 128;
  const int bcol = tj * 128;

  const int rtA0 = ti * 8 + wid * 4;  // this wave's 4 A row-tiles
  const int rtB0 = tj * 8;            // all 8 B row-tiles (Gram columns)

  f32x4 acc[4][8];
  #pragma unroll
  for (int m = 0; m < 4; ++m)
    #pragma unroll
    for (int n = 0; n < 8; ++n) acc[m][n] = f32x4{0.f, 0.f, 0.f, 0.f};

  if (MODE == 0) {
    const unsigned short* pa =
        dbf2 + (((size_t)b * 8) * 64 + rtA0) * 512 + (size_t)lane * 8;
    const unsigned short* pb =
        dbf2 + (((size_t)b * 8) * 64 + rtB0) * 512 + (size_t)lane * 8;
    bf16x8 af[4], bf[8], nf[4];
    #pragma unroll
    for (int m = 0; m < 4; ++m)
      af[m] = *reinterpret_cast<const bf16x8*>(pa + m * 512);
    #pragma unroll
    for (int n = 0; n < 8; ++n)
      bf[n] = *reinterpret_cast<const bf16x8*>(pb + n * 512);
    #pragma unroll
    for (int kg = 0; kg < 8; ++kg) {
      if (kg < 7) {
        #pragma unroll
        for (int m = 0; m < 4; ++m)
          nf[m] = *reinterpret_cast<const bf16x8*>(pa + 32768 + m * 512);
      }
      #pragma unroll
      for (int n = 0; n < 8; ++n) {
        #pragma unroll
        for (int m = 0; m < 4; ++m)
          acc[m][n] = __builtin_amdgcn_mfma_f32_16x16x32_bf16(af[m], bf[n], acc[m][n], 0, 0, 0);
        if (kg < 7)
          bf[n] = *reinterpret_cast<const bf16x8*>(pb + 32768 + n * 512);  // bf[n] dead
      }
      if (kg < 7) {
        #pragma unroll
        for (int m = 0; m < 4; ++m) af[m] = nf[m];
        pa += 32768; pb += 32768;
      }
    }
  } else {
    const float* pbase = dvec + (size_t)b * NS * DD + (lane >> 4) * 8;
    #pragma unroll
    for (int kg = 0; kg < 8; ++kg) {
      bf16x8 af[4], bf[8];
      #pragma unroll
      for (int m = 0; m < 4; ++m) {
        const float* p = pbase + (size_t)((rtA0 + m) * 16 + (lane & 15)) * DD + kg * 32;
        float4 v0 = reinterpret_cast<const float4*>(p)[0];
        float4 v1 = reinterpret_cast<const float4*>(p)[1];
        af[m][0] = (short)f2bf(v0.x); af[m][1] = (short)f2bf(v0.y);
        af[m][2] = (short)f2bf(v0.z); af[m][3] = (short)f2bf(v0.w);
        af[m][4] = (short)f2bf(v1.x); af[m][5] = (short)f2bf(v1.y);
        af[m][6] = (short)f2bf(v1.z); af[m][7] = (short)f2bf(v1.w);
      }
      #pragma unroll
      for (int n = 0; n < 8; ++n) {
        const float* p = pbase + (size_t)((rtB0 + n) * 16 + (lane & 15)) * DD + kg * 32;
        float4 v0 = reinterpret_cast<const float4*>(p)[0];
        float4 v1 = reinterpret_cast<const float4*>(p)[1];
        bf[n][0] = (short)f2bf(v0.x); bf[n][1] = (short)f2bf(v0.y);
        bf[n][2] = (short)f2bf(v0.z); bf[n][3] = (short)f2bf(v0.w);
        bf[n][4] = (short)f2bf(v1.x); bf[n][5] = (short)f2bf(v1.y);
        bf[n][6] = (short)f2bf(v1.z); bf[n][7] = (short)f2bf(v1.w);
      }
      #pragma unroll
      for (int m = 0; m < 4; ++m)
        #pragma unroll
        for (int n = 0; n < 8; ++n)
          acc[m][n] = __builtin_amdgcn_mfma_f32_16x16x32_bf16(af[m], bf[n], acc[m][n], 0, 0, 0);
    }
  }

  // ---- epilogue, two-pass: branch-free d2 min scan; rare kd path under one
  // ballot. exp(-dist) is sub-f32-eps vs S once d2 > THR -> bit-identical. ----
  const float* sqb = sq + (size_t)b * NS;
  const int hi = lane >> 4, lo = lane & 15;
  float sqc[8];
  #pragma unroll
  for (int n = 0; n < 8; ++n) sqc[n] = sqb[bcol + n * 16 + lo];
  float dmin = 1e30f;
  #pragma unroll
  for (int m = 0; m < 4; ++m) {
    #pragma unroll
    for (int j = 0; j < 4; ++j) {
      const int r = brow + wid * 64 + m * 16 + hi * 4 + j;
      const float sqr = sqb[r];
      #pragma unroll
      for (int n = 0; n < 8; ++n) {
        const int c = bcol + n * 16 + lo;
        const float d2 = fmaxf(sqr + sqc[n] - 2.0f * acc[m][n][j], 0.0f);
        dmin = fminf(dmin, (r < c) ? d2 : 1e30f);
      }
    }
  }
  float wsum = 0.f;
  if (__any(dmin < THR)) {
    // pair (r,c), r<c: kd^2*(W[r][c]+W[c][r]) - 2*kd*(W[r][c]S[r][c]+W[c][r]S[c][r])
    float lsum = 0.f;
    #pragma unroll
    for (int m = 0; m < 4; ++m) {
      #pragma unroll
      for (int j = 0; j < 4; ++j) {
        const int r = brow + wid * 64 + m * 16 + hi * 4 + j;
        const float sqr = sqb[r];
        #pragma unroll
        for (int n = 0; n < 8; ++n) {
          const int c = bcol + n * 16 + lo;
          const float d2 = fmaxf(sqr + sqc[n] - 2.0f * acc[m][n][j], 0.0f);
          if ((r < c) && (d2 < THR)) {
            const float kd = __expf(-sqrtf(d2));
            const float wrc = W[(size_t)r * NS + c];
            const float wcr = W[(size_t)c * NS + r];
            const float src_ = S[(size_t)r * NS + c];
            const float scr = S[(size_t)c * NS + r];
            lsum = fmaf(kd, kd * (wrc + wcr) - 2.0f * fmaf(wrc, src_, wcr * scr), lsum);
          }
        }
      }
    }
    #pragma unroll
    for (int off = 32; off > 0; off >>= 1) lsum += __shfl_xor(lsum, off, 64);
    wsum = lsum;
  }
  // unconditional per-(block,wave) partial (poison-safe, no atomics)
  if (lane == 0) npart[(size_t)bid * 2 + wid] = wsum;
}

// ---- final: npart[b*72 .. +72) per batch; out = sum_b 2*sqrt(C+n_b)/sqrt(D) ----
__global__ void final_kernel(const float* __restrict__ npart,
                             const float* __restrict__ dpart,
                             const float* __restrict__ cpart,
                             float* __restrict__ out) {
  const int lane = threadIdx.x;
  float dsum = 0.f, csum = 0.f;
  #pragma unroll
  for (int j = 0; j < 16; ++j) {
    dsum += dpart[lane + 64 * j];
    csum += cpart[lane + 64 * j];
  }
  #pragma unroll
  for (int off = 32; off > 0; off >>= 1) {
    dsum += __shfl_xor(dsum, off, 64);
    csum += __shfl_xor(csum, off, 64);
  }
  // lane b: reduce its batch's 36 tiles x 2 waves = 72 contiguous floats
  float nb = 0.f;
  const f32x4* np = reinterpret_cast<const f32x4*>(npart + (size_t)lane * 72);
  #pragma unroll
  for (int j = 0; j < 18; ++j) {
    f32x4 v = np[j];
    nb += v[0] + v[1] + v[2] + v[3];
  }
  float v = 2.0f * sqrtf(csum + nb);
  #pragma unroll
  for (int off = 32; off > 0; off >>= 1) v += __shfl_xor(v, off, 64);
  if (lane == 0) out[0] = v / sqrtf(dsum);
}

extern "C" void kernel_launch(void* const* d_in, const int* in_sizes, int n_in,
                              void* d_out, int out_size, void* d_ws, size_t ws_size,
                              hipStream_t stream) {
  const float* dvec = (const float*)d_in[0];
  const float* S = (const float*)d_in[1];
  const float* W = (const float*)d_in[2];
  float* out = (float*)d_out;

  const size_t bf_bytes = (size_t)NB * NS * DD * sizeof(unsigned short);  // 32 MiB
  const size_t sq_bytes = (size_t)NB * NS * sizeof(float);                // 256 KiB
  const size_t small_bytes = sq_bytes + (4608 + 1024 + 1024) * sizeof(float);
  const bool full = ws_size >= bf_bytes + small_bytes;

  unsigned short* dbf2;
  float* sqp;
  if (full) {
    dbf2 = (unsigned short*)d_ws;
    sqp = (float*)((char*)d_ws + bf_bytes);
  } else {
    dbf2 = nullptr;
    sqp = (float*)d_ws;
  }
  float* npart = sqp + (size_t)NB * NS;    // 4608 floats (2304 blocks x 2 waves)
  float* dpart = npart + 4608;             // 1024
  float* cpart = dpart + 1024;             // 1024

  prep_kernel<<<4096 + 1024, 128, 0, stream>>>(dvec, dbf2, sqp, S, W,
                                               dpart, cpart, full ? 1 : 0);
  if (full)
    main_kernel<0><<<NT * NB, 128, 0, stream>>>(dvec, dbf2, sqp, npart, S, W);
  else
    main_kernel<1><<<NT * NB, 128, 0, stream>>>(dvec, dbf2, sqp, npart, S, W);
  final_kernel<<<1, 64, 0, stream>>>(npart, dpart, cpart, out);
}

// Round 13
// 42.106 us; speedup vs baseline: 1.3599x; 1.3599x over previous
//
#include <hip/hip_runtime.h>
#include <hip/hip_bf16.h>

#define NB 64
#define NS 1024
#define DD 256
#define NT 36          // upper-triangular 8x8 tile count
#define THR 120.0f     // dist^2 below which exp(-dist) can matter

typedef __attribute__((ext_vector_type(4))) float f32x4;
typedef __attribute__((ext_vector_type(8))) short bf16x8;
typedef unsigned long long u64;

__device__ __forceinline__ unsigned short f2bf(float x) {
  union { float f; unsigned int u; } c; c.f = x;
  unsigned int r = c.u + 0x7fffu + ((c.u >> 16) & 1u);
  return (unsigned short)(r >> 16);
}

// pack 4 f32 -> 4 fp8 e4m3 bytes (hardware cvt)
__device__ __forceinline__ unsigned int pk_fp8x4(float x, float y, float z, float w) {
  unsigned int v = 0;
#if __has_builtin(__builtin_amdgcn_cvt_pk_fp8_f32)
  v = __builtin_amdgcn_cvt_pk_fp8_f32(x, y, v, false);
  v = __builtin_amdgcn_cvt_pk_fp8_f32(z, w, v, true);
#else
  asm("v_cvt_pk_fp8_f32 %0, %1, %2" : "+v"(v) : "v"(x), "v"(y));
  asm("v_cvt_pk_fp8_f32 %0, %1, %2 op_sel:[0,0,1]" : "+v"(v) : "v"(z), "v"(w));
#endif
  return v;
}

// dbf3 layout (kg-major fp8 fragment blocks): block(b, kg, rt) = (b*8+kg)*64+rt,
// 512 BYTES each. Slot s (0..63) holds 8 fp8: row = rt*16 + (s&15),
// k = kg*32 + (s>>4)*8 + 0..7. A wave's fragment load is one coalesced 512B
// global_load_dwordx2 (lane l reads slot l). fp8 e4m3 Gram precision is ample:
// G only reaches the output through the d2<THR gate and kd<=1.7e-5 terms.

// ---- prep: 4096 blocks x 128 thr (2 waves), one 16-row tile per block.
//      Phase A: wave w loads rows w*8..w*8+7 (coalesced 1KB f32), exact-f32 sq,
//      cvt->fp8, granule-XOR-swizzled LDS write (2-way bank = free).
//      Phase B (after barrier): wave w emits kg w*4..w*4+3: swizzled
//      ds_read_b64 -> coalesced 512B fragment store.
//      XCD-matched: XCD k (= px&7) writes batches [8k,8k+8) = main's readers.
__global__ __launch_bounds__(128) void prep_kernel(const float* __restrict__ din,
                                                   unsigned char* __restrict__ dbf3,
                                                   float* __restrict__ sq,
                                                   int write_bf) {
  __shared__ unsigned char T[16][256];           // 4 KB fp8 tile
  const int px = (int)blockIdx.x;
  const int wid = (int)threadIdx.x >> 6;         // 0,1
  const int l = (int)threadIdx.x & 63;
  const int tb = (px & 7) * 512 + (px >> 3);     // tile task 0..4095
  const int b = tb >> 6, rt = tb & 63;
  const float4* src =
      reinterpret_cast<const float4*>(din + ((size_t)b * NS + rt * 16) * DD) + l;
  #pragma unroll
  for (int j = 0; j < 8; ++j) {
    const int ri = wid * 8 + j;                  // row within tile
    float4 v = src[ri * 64];                     // row stride 256 f = 64 float4
    float s = v.x * v.x + v.y * v.y + v.z * v.z + v.w * v.w;
    #pragma unroll
    for (int off = 32; off > 0; off >>= 1) s += __shfl_xor(s, off, 64);
    if (l == 0) sq[(size_t)b * NS + rt * 16 + ri] = s;
    if (write_bf) {
      // lane l holds 4B fp8-granule g=l of row ri; swizzled pos g^( (ri&15)<<2 )
      const unsigned int w4 = pk_fp8x4(v.x, v.y, v.z, v.w);
      const int gp = l ^ ((ri & 15) << 2);
      *reinterpret_cast<unsigned int*>(&T[ri][gp * 4]) = w4;
    }
  }
  if (!write_bf) return;
  __syncthreads();
  // Phase B: slot l of kg-block = row (l&15), granules gd = kg*8+(l>>4)*2,+1
  // (consecutive, low2 of XOR const are 0 -> b64 read ok), swizzle ^((l&15)<<2)
  unsigned char* dst = dbf3 + (((size_t)b * 8) * 64 + rt) * 512 + (size_t)l * 8;
  #pragma unroll
  for (int q = 0; q < 4; ++q) {
    const int kg = wid * 4 + q;
    const int gd = kg * 8 + (l >> 4) * 2;
    const int gp = gd ^ ((l & 15) << 2);
    const u64 frag = *reinterpret_cast<const u64*>(&T[l & 15][gp * 4]);
    *reinterpret_cast<u64*>(dst + (size_t)kg * 64 * 512) = frag;
  }
}

// ---- main: blocks [0,2304): barrier-free LDS-free fp8-MFMA Gram (one batch,
// one upper-tri tile; 4 waves x 64x64). Fragment loads hit the LOCAL XCD L2.
// Software prefetch distance 1. blocks [2304,2816): denom2/C partials.
template <int MODE>
__global__ __launch_bounds__(256, 2) void main_kernel(
    const float* __restrict__ dvec, const unsigned char* __restrict__ dbf3,
    const float* __restrict__ sq, const float* __restrict__ S,
    const float* __restrict__ W, float* __restrict__ npart,
    float* __restrict__ dpart, float* __restrict__ cpart) {
  const int tid = threadIdx.x;
  const int lane = tid & 63;
  const int wid = tid >> 6;
  const int orig = (int)blockIdx.x;

  if (orig >= NT * NB) {
    // ---- denomC partials: blk in [0,512), 256 thr x 2 float4 each ----
    const int blk = orig - NT * NB;
    const int base = blk * 256 + tid;
    float dsum = 0.f, csum = 0.f;
    #pragma unroll
    for (int rpt = 0; rpt < 2; ++rpt) {
      const int idx = base + rpt * 131072;
      float4 w = reinterpret_cast<const float4*>(W)[idx];
      float4 s4 = reinterpret_cast<const float4*>(S)[idx];
      const int e0 = idx << 2;
      const int r = e0 >> 10, c0 = e0 & 1023;
      float wv[4] = {w.x, w.y, w.z, w.w};
      float sv[4] = {s4.x, s4.y, s4.z, s4.w};
      #pragma unroll
      for (int i = 0; i < 4; ++i) {
        const bool dg = (c0 + i) == r;
        const float a = wv[i] - (dg ? 1.0f : 0.0f);
        dsum = fmaf(a, a, dsum);
        const float bq = dg ? (1.0f - sv[i]) : sv[i];
        csum = fmaf(wv[i] * bq, bq, csum);   // W binary: W^2 == W
      }
    }
    #pragma unroll
    for (int off = 32; off > 0; off >>= 1) {
      dsum += __shfl_xor(dsum, off, 64);
      csum += __shfl_xor(csum, off, 64);
    }
    __shared__ float redD[4], redC[4];
    if (lane == 0) { redD[wid] = dsum; redC[wid] = csum; }
    __syncthreads();
    if (tid == 0) {
      dpart[blk] = redD[0] + redD[1] + redD[2] + redD[3];
      cpart[blk] = redC[0] + redC[1] + redC[2] + redC[3];
    }
    return;
  }

  const int wr = wid >> 1;
  const int wc = wid & 1;
  // XCD-chunked bijective swizzle (2304 = 8 * 288): XCD k gets bids
  // [288k, 288k+288) -> b in [8k, 8k+8) (t-fast) = the batches its L2 holds.
  const int bid = (orig & 7) * (NT * NB / 8) + (orig >> 3);
  const int t = bid % NT;
  const int b = bid / NT;
  int u = t, ti = 0;
  while (u >= 8 - ti) { u -= 8 - ti; ++ti; }
  const int tj = ti + u;
  const int brow = ti * 128;
  const int bcol = tj * 128;

  const int rtA0 = ti * 8 + wr * 4;   // A row-tiles (16 rows each)
  const int rtB0 = tj * 8 + wc * 4;   // B row-tiles (Gram columns)

  f32x4 acc[4][4];
  #pragma unroll
  for (int m = 0; m < 4; ++m)
    #pragma unroll
    for (int n = 0; n < 4; ++n) acc[m][n] = f32x4{0.f, 0.f, 0.f, 0.f};

  if (MODE == 0) {
    const unsigned char* pa =
        dbf3 + (((size_t)b * 8) * 64 + rtA0) * 512 + (size_t)lane * 8;
    const unsigned char* pb =
        dbf3 + (((size_t)b * 8) * 64 + rtB0) * 512 + (size_t)lane * 8;
    u64 af[4], bf[4], nf[4];
    #pragma unroll
    for (int m = 0; m < 4; ++m)
      af[m] = *reinterpret_cast<const u64*>(pa + m * 512);
    #pragma unroll
    for (int n = 0; n < 4; ++n)
      bf[n] = *reinterpret_cast<const u64*>(pb + n * 512);
    #pragma unroll
    for (int kg = 0; kg < 8; ++kg) {
      if (kg < 7) {
        #pragma unroll
        for (int m = 0; m < 4; ++m)
          nf[m] = *reinterpret_cast<const u64*>(pa + 32768 + m * 512);
      }
      #pragma unroll
      for (int n = 0; n < 4; ++n) {
        #pragma unroll
        for (int m = 0; m < 4; ++m)
          acc[m][n] = __builtin_amdgcn_mfma_f32_16x16x32_fp8_fp8(
              (long)af[m], (long)bf[n], acc[m][n], 0, 0, 0);
        if (kg < 7)
          bf[n] = *reinterpret_cast<const u64*>(pb + 32768 + n * 512);  // bf[n] dead
      }
      if (kg < 7) {
        #pragma unroll
        for (int m = 0; m < 4; ++m) af[m] = nf[m];
        pa += 32768; pb += 32768;
      }
    }
  } else {
    const float* pbase = dvec + (size_t)b * NS * DD + (lane >> 4) * 8;
    #pragma unroll
    for (int kg = 0; kg < 8; ++kg) {
      bf16x8 af[4], bf[4];
      #pragma unroll
      for (int m = 0; m < 4; ++m) {
        const float* p = pbase + (size_t)((rtA0 + m) * 16 + (lane & 15)) * DD + kg * 32;
        float4 v0 = reinterpret_cast<const float4*>(p)[0];
        float4 v1 = reinterpret_cast<const float4*>(p)[1];
        af[m][0] = (short)f2bf(v0.x); af[m][1] = (short)f2bf(v0.y);
        af[m][2] = (short)f2bf(v0.z); af[m][3] = (short)f2bf(v0.w);
        af[m][4] = (short)f2bf(v1.x); af[m][5] = (short)f2bf(v1.y);
        af[m][6] = (short)f2bf(v1.z); af[m][7] = (short)f2bf(v1.w);
      }
      #pragma unroll
      for (int n = 0; n < 4; ++n) {
        const float* p = pbase + (size_t)((rtB0 + n) * 16 + (lane & 15)) * DD + kg * 32;
        float4 v0 = reinterpret_cast<const float4*>(p)[0];
        float4 v1 = reinterpret_cast<const float4*>(p)[1];
        bf[n][0] = (short)f2bf(v0.x); bf[n][1] = (short)f2bf(v0.y);
        bf[n][2] = (short)f2bf(v0.z); bf[n][3] = (short)f2bf(v0.w);
        bf[n][4] = (short)f2bf(v1.x); bf[n][5] = (short)f2bf(v1.y);
        bf[n][6] = (short)f2bf(v1.z); bf[n][7] = (short)f2bf(v1.w);
      }
      #pragma unroll
      for (int m = 0; m < 4; ++m)
        #pragma unroll
        for (int n = 0; n < 4; ++n)
          acc[m][n] = __builtin_amdgcn_mfma_f32_16x16x32_bf16(af[m], bf[n], acc[m][n], 0, 0, 0);
    }
  }

  // ---- epilogue, two-pass: branch-free d2 min scan; rare kd path under one
  // ballot. exp(-dist) is sub-f32-eps vs S once d2 > THR. ----
  const float* sqb = sq + (size_t)b * NS;
  const int hi = lane >> 4, lo = lane & 15;
  float sqc[4];
  #pragma unroll
  for (int n = 0; n < 4; ++n) sqc[n] = sqb[bcol + wc * 64 + n * 16 + lo];
  float dmin = 1e30f;
  #pragma unroll
  for (int m = 0; m < 4; ++m) {
    #pragma unroll
    for (int j = 0; j < 4; ++j) {
      const int r = brow + wr * 64 + m * 16 + hi * 4 + j;
      const float sqr = sqb[r];
      #pragma unroll
      for (int n = 0; n < 4; ++n) {
        const int c = bcol + wc * 64 + n * 16 + lo;
        const float d2 = fmaxf(sqr + sqc[n] - 2.0f * acc[m][n][j], 0.0f);
        dmin = fminf(dmin, (r < c) ? d2 : 1e30f);
      }
    }
  }
  float wsum = 0.f;
  if (__any(dmin < THR)) {
    // pair (r,c), r<c: kd^2*(W[r][c]+W[c][r]) - 2*kd*(W[r][c]S[r][c]+W[c][r]S[c][r])
    float lsum = 0.f;
    #pragma unroll
    for (int m = 0; m < 4; ++m) {
      #pragma unroll
      for (int j = 0; j < 4; ++j) {
        const int r = brow + wr * 64 + m * 16 + hi * 4 + j;
        const float sqr = sqb[r];
        #pragma unroll
        for (int n = 0; n < 4; ++n) {
          const int c = bcol + wc * 64 + n * 16 + lo;
          const float d2 = fmaxf(sqr + sqc[n] - 2.0f * acc[m][n][j], 0.0f);
          if ((r < c) && (d2 < THR)) {
            const float kd = __expf(-sqrtf(d2));
            const float wrc = W[(size_t)r * NS + c];
            const float wcr = W[(size_t)c * NS + r];
            const float src_ = S[(size_t)r * NS + c];
            const float scr = S[(size_t)c * NS + r];
            lsum = fmaf(kd, kd * (wrc + wcr) - 2.0f * fmaf(wrc, src_, wcr * scr), lsum);
          }
        }
      }
    }
    #pragma unroll
    for (int off = 32; off > 0; off >>= 1) lsum += __shfl_xor(lsum, off, 64);
    wsum = lsum;
  }
  // unconditional per-(block,wave) partial (poison-safe, no atomics)
  if (lane == 0) npart[(size_t)bid * 4 + wid] = wsum;
}

// ---- final: npart[b*144 .. +144) per batch; out = sum_b 2*sqrt(C+n_b)/sqrt(D) ----
__global__ void final_kernel(const float* __restrict__ npart,
                             const float* __restrict__ dpart,
                             const float* __restrict__ cpart,
                             float* __restrict__ out) {
  const int lane = threadIdx.x;
  float dsum = 0.f, csum = 0.f;
  #pragma unroll
  for (int j = 0; j < 8; ++j) {
    dsum += dpart[lane + 64 * j];
    csum += cpart[lane + 64 * j];
  }
  #pragma unroll
  for (int off = 32; off > 0; off >>= 1) {
    dsum += __shfl_xor(dsum, off, 64);
    csum += __shfl_xor(csum, off, 64);
  }
  // lane b: reduce its batch's 36 tiles x 4 waves = 144 contiguous floats
  float nb = 0.f;
  const f32x4* np = reinterpret_cast<const f32x4*>(npart + (size_t)lane * 144);
  #pragma unroll
  for (int j = 0; j < 36; ++j) {
    f32x4 v = np[j];
    nb += v[0] + v[1] + v[2] + v[3];
  }
  float v = 2.0f * sqrtf(csum + nb);
  #pragma unroll
  for (int off = 32; off > 0; off >>= 1) v += __shfl_xor(v, off, 64);
  if (lane == 0) out[0] = v / sqrtf(dsum);
}

extern "C" void kernel_launch(void* const* d_in, const int* in_sizes, int n_in,
                              void* d_out, int out_size, void* d_ws, size_t ws_size,
                              hipStream_t stream) {
  const float* dvec = (const float*)d_in[0];
  const float* S = (const float*)d_in[1];
  const float* W = (const float*)d_in[2];
  float* out = (float*)d_out;

  const size_t bf_bytes = (size_t)NB * NS * DD;                           // 16 MiB fp8
  const size_t sq_bytes = (size_t)NB * NS * sizeof(float);                // 256 KiB
  const size_t small_bytes = sq_bytes + (9216 + 512 + 512) * sizeof(float);
  const bool full = ws_size >= bf_bytes + small_bytes;

  unsigned char* dbf3;
  float* sqp;
  if (full) {
    dbf3 = (unsigned char*)d_ws;
    sqp = (float*)((char*)d_ws + bf_bytes);
  } else {
    dbf3 = nullptr;
    sqp = (float*)d_ws;
  }
  float* npart = sqp + (size_t)NB * NS;    // 9216 floats (2304 blocks x 4 waves)
  float* dpart = npart + 9216;             // 512
  float* cpart = dpart + 512;              // 512

  prep_kernel<<<4096, 128, 0, stream>>>(dvec, dbf3, sqp, full ? 1 : 0);
  if (full)
    main_kernel<0><<<NT * NB + 512, 256, 0, stream>>>(dvec, dbf3, sqp, S, W,
                                                      npart, dpart, cpart);
  else
    main_kernel<1><<<NT * NB + 512, 256, 0, stream>>>(dvec, dbf3, sqp, S, W,
                                                      npart, dpart, cpart);
  final_kernel<<<1, 64, 0, stream>>>(npart, dpart, cpart, out);
}